// Round 12
// baseline (89.989 us; speedup 1.0000x reference)
//
#include <hip/hip_runtime.h>

static constexpr int N_NODES = 50000;
static constexpr int N_EDGES = 800000;

static constexpr int NBK      = 196;     // buckets of 256 dst-nodes (dst>>8)
static constexpr int BCAP     = 5120;    // slots/bucket (mean 4096, +16 sigma)
static constexpr int MAXE     = BCAP / 512;   // 10 elems/thread in k_build
static constexpr int BIN_TILE = 2048;    // edges per bin block
static constexpr int BIN_BLOCKS = (N_EDGES + BIN_TILE - 1) / BIN_TILE;  // 391
static constexpr int PRE1_TILES  = (N_NODES + 15) / 16;                 // 3125
static constexpr int PRE1_BLOCKS = (PRE1_TILES + 3) / 4;                // 782

typedef __attribute__((ext_vector_type(8))) short   bf16x8;
typedef __attribute__((ext_vector_type(4))) float   floatx4;

// f32 -> bf16 (RNE) as raw u16
__device__ __forceinline__ unsigned short f2b(float f) {
    union { float f; unsigned u; } v; v.f = f;
    unsigned r = v.u + 0x7FFFu + ((v.u >> 16) & 1u);
    return (unsigned short)(r >> 16);
}
__device__ __forceinline__ float blo(unsigned v) {
    union { unsigned u; float f; } c; c.u = v << 16; return c.f;
}
__device__ __forceinline__ float bhi(unsigned v) {
    union { unsigned u; float f; } c; c.u = v & 0xffff0000u; return c.f;
}
__device__ __forceinline__ unsigned pk2(float a, float b) {
    return (unsigned)f2b(a) | ((unsigned)f2b(b) << 16);
}

// ---------------------------------------------------------------------------
// Fused dispatch 1: blocks [0, BIN_BLOCKS) bin edges into 196 dst-buckets;
// blocks [BIN_BLOCKS, +PRE1_BLOCKS) run the MFMA layer-1 projection.
// ---------------------------------------------------------------------------
__device__ __forceinline__ void bin_body(
    int bb, const int* __restrict__ srcv, const int* __restrict__ dstv,
    int* __restrict__ bcnt, unsigned* __restrict__ epair)
{
    __shared__ uint2 stage[BIN_TILE];      // 16 KB
    __shared__ int cnt[256];
    __shared__ int scn[256];
    __shared__ int pref[NBK];
    __shared__ int gbase[NBK];

    int tid   = threadIdx.x;
    int base  = bb * BIN_TILE;
    int tileN = min(BIN_TILE, N_EDGES - base);

    cnt[tid] = 0;
    __syncthreads();

    int ss[8], dd[8], sl[8];
#pragma unroll
    for (int j = 0; j < 8; ++j) {
        int i = tid + j * 256;
        ss[j] = -1; dd[j] = 0; sl[j] = 0;
        if (i < tileN) {
            ss[j] = srcv[base + i];
            dd[j] = dstv[base + i];
            sl[j] = atomicAdd(&cnt[dd[j] >> 8], 1);   // LDS only
        }
    }
    __syncthreads();

    // exclusive scan of cnt[0..255]
    int own = cnt[tid];
    scn[tid] = own;
    __syncthreads();
    for (int off = 1; off < 256; off <<= 1) {
        int t = (tid >= off) ? scn[tid - off] : 0;
        __syncthreads();
        scn[tid] += t;
        __syncthreads();
    }
    if (tid < NBK) {
        pref[tid]  = scn[tid] - cnt[tid];
        gbase[tid] = tid * BCAP + atomicAdd(&bcnt[tid], cnt[tid]);
    }
    __syncthreads();

#pragma unroll
    for (int j = 0; j < 8; ++j) {
        if (ss[j] >= 0) {
            int b = dd[j] >> 8;
            stage[pref[b] + sl[j]] = uint2{(unsigned)ss[j], (unsigned)dd[j]};
        }
    }
    __syncthreads();

    for (int i = tid; i < tileN; i += 256) {
        uint2 pd = stage[i];
        int b = (int)(pd.y >> 8);
        epair[(size_t)gbase[b] + (i - pref[b])] = (pd.x << 8) | (pd.y & 255u);
    }
}

__device__ __forceinline__ void pre1_body(
    int bb, const float* __restrict__ x,
    const float* __restrict__ Wrel, const float* __restrict__ Wroot,
    const float* __restrict__ bias,
    unsigned short* __restrict__ u1, unsigned short* __restrict__ r1)
{
    int lane = threadIdx.x & 63;
    int c15  = lane & 15;
    int q    = lane >> 4;

    bf16x8 bf[2][4][2];
#pragma unroll
    for (int mat = 0; mat < 2; ++mat) {
        const float* W = mat ? Wroot : Wrel;
#pragma unroll
        for (int ct = 0; ct < 4; ++ct) {
            int c = ct * 16 + c15;
#pragma unroll
            for (int kf = 0; kf < 2; ++kf) {
                int kb = kf * 32 + q * 8;
                bf16x8 f;
#pragma unroll
                for (int j = 0; j < 8; ++j)
                    f[j] = (short)f2b(W[(kb + j) * 64 + c]);
                bf[mat][ct][kf] = f;
            }
        }
    }
    float bv[4];
#pragma unroll
    for (int ct = 0; ct < 4; ++ct) bv[ct] = bias[ct * 16 + c15];

    int tile = bb * 4 + (threadIdx.x >> 6);
    if (tile * 16 >= N_NODES) return;
    int row0 = tile * 16;

    const float* xr = x + (size_t)(row0 + c15) * 64;
    bf16x8 a0, a1;
#pragma unroll
    for (int j = 0; j < 8; ++j) {
        a0[j] = (short)f2b(xr[q * 8 + j]);
        a1[j] = (short)f2b(xr[32 + q * 8 + j]);
    }

    floatx4 z = {0.f, 0.f, 0.f, 0.f};
    floatx4 acc[2][4];
#pragma unroll
    for (int mat = 0; mat < 2; ++mat)
#pragma unroll
        for (int ct = 0; ct < 4; ++ct) {
            floatx4 a = __builtin_amdgcn_mfma_f32_16x16x32_bf16(a0, bf[mat][ct][0], z, 0, 0, 0);
            acc[mat][ct] = __builtin_amdgcn_mfma_f32_16x16x32_bf16(a1, bf[mat][ct][1], a, 0, 0, 0);
        }

    // sigma-order write: position p=(lane&15)*4+ct <-> true col ct*16+(lane&15)
#pragma unroll
    for (int reg = 0; reg < 4; ++reg) {
        int row = row0 + q * 4 + reg;
        uint2 uu, rr;
        uu.x = pk2(acc[0][0][reg],          acc[0][1][reg]);
        uu.y = pk2(acc[0][2][reg],          acc[0][3][reg]);
        rr.x = pk2(acc[1][0][reg] + bv[0],  acc[1][1][reg] + bv[1]);
        rr.y = pk2(acc[1][2][reg] + bv[2],  acc[1][3][reg] + bv[3]);
        *reinterpret_cast<uint2*>(u1 + (size_t)row * 64 + c15 * 4) = uu;
        *reinterpret_cast<uint2*>(r1 + (size_t)row * 64 + c15 * 4) = rr;
    }
}

__global__ __launch_bounds__(256) void k_binpre1(
    const int* __restrict__ srcv, const int* __restrict__ dstv,
    int* __restrict__ bcnt, unsigned* __restrict__ epair,
    const float* __restrict__ x,
    const float* __restrict__ Wrel, const float* __restrict__ Wroot,
    const float* __restrict__ bias,
    unsigned short* __restrict__ u1, unsigned short* __restrict__ r1)
{
    if ((int)blockIdx.x < BIN_BLOCKS)
        bin_body(blockIdx.x, srcv, dstv, bcnt, epair);
    else
        pre1_body(blockIdx.x - BIN_BLOCKS, x, Wrel, Wroot, bias, u1, r1);
}

// ---------------------------------------------------------------------------
// Dispatch 2: one block per 256-node bucket; single pass over packed pairs in
// statically-indexed registers; LDS histogram+scan; atomic-free scatter.
// ---------------------------------------------------------------------------
__global__ __launch_bounds__(512) void k_build(
    const unsigned* __restrict__ epair, const int* __restrict__ bcnt,
    int* __restrict__ offsets, int* __restrict__ esrc)
{
    __shared__ int cnt[256];
    __shared__ int scn[256];
    __shared__ int start[256];
    __shared__ int s_base;

    int b = blockIdx.x;
    int t = threadIdx.x;
    int node0 = b << 8;
    int ncnt  = min(256, N_NODES - node0);
    int beg   = b * BCAP;
    int m     = bcnt[b];

    if (t < 256) cnt[t] = 0;
    __syncthreads();

    unsigned ev[MAXE]; int sl[MAXE];
#pragma unroll
    for (int j = 0; j < MAXE; ++j) {
        int i = t + j * 512;
        ev[j] = 0; sl[j] = -1;
        if (i < m) {
            ev[j] = epair[beg + i];
            sl[j] = atomicAdd(&cnt[ev[j] & 255u], 1);
        }
    }

    // bucket global base = total size of earlier buckets (first wave)
    if (t < 64) {
        int pre = 0;
#pragma unroll
        for (int k = 0; k < 4; ++k) {
            int i = t + (k << 6);
            if (i < b) pre += bcnt[i];
        }
        for (int off = 1; off < 64; off <<= 1) pre += __shfl_xor(pre, off);
        if (t == 0) s_base = pre;
    }
    __syncthreads();

    // exclusive scan of cnt[0..255]
    int own = (t < 256) ? cnt[t] : 0;
    if (t < 256) scn[t] = own;
    __syncthreads();
    for (int off = 1; off < 256; off <<= 1) {
        int v = (t < 256 && t >= off) ? scn[t - off] : 0;
        __syncthreads();
        if (t < 256) scn[t] += v;
        __syncthreads();
    }
    if (t < 256) {
        int st = s_base + scn[t] - own;
        start[t] = st;
        if (t < ncnt) offsets[node0 + t] = st;
    }
    if (b == 0 && t == 0) offsets[N_NODES] = N_EDGES;
    __syncthreads();

#pragma unroll
    for (int j = 0; j < MAXE; ++j) {
        if (sl[j] >= 0)
            esrc[start[ev[j] & 255u] + sl[j]] = (int)(ev[j] >> 8);
    }
}

// ---------------------------------------------------------------------------
// FUSED aggregate-1 + layer-2 projection, WAVE-PER-NODE:
// block = 16 waves = 16 nodes, each wave gathers ONE node in parallel
// (full node TLP preserved), h rows -> XOR-swizzled LDS; after the barrier
// wave0 projects u2 = h@Wrel2, wave1 projects r2 = h@Wroot2+b2 (MFMA).
// ---------------------------------------------------------------------------
__global__ __launch_bounds__(1024) void k_aggf(
    const unsigned short* __restrict__ u1,
    const unsigned short* __restrict__ r1,
    const int* __restrict__ offsets, const int* __restrict__ esrc,
    const float* __restrict__ Wrel,    // [64][32] f32
    const float* __restrict__ Wroot,   // [64][32] f32
    const float* __restrict__ bias,    // [32] f32
    unsigned short* __restrict__ u2,
    unsigned short* __restrict__ r2)
{
    __shared__ unsigned short hlds[16 * 64];   // 2 KB, swizzled rows

    int w    = threadIdx.x >> 6;   // 0..15 = local node
    int lane = threadIdx.x & 63;
    int j    = lane & 7;           // 8 lanes/row, 16B each
    int slot = lane >> 3;          // 8 edge slots

    int node = blockIdx.x * 16 + w;   // N_NODES = 3125*16 exactly
    if (node < N_NODES) {
        int beg = offsets[node], end = offsets[node + 1];
        float s0 = 0.f, s1 = 0.f, s2 = 0.f, s3 = 0.f;
        float s4 = 0.f, s5 = 0.f, s6 = 0.f, s7 = 0.f;
        for (int e = beg + slot; e < end; e += 8) {
            int sv = esrc[e];
            uint4 v = *reinterpret_cast<const uint4*>(u1 + (size_t)sv * 64 + j * 8);
            s0 += blo(v.x); s1 += bhi(v.x);
            s2 += blo(v.y); s3 += bhi(v.y);
            s4 += blo(v.z); s5 += bhi(v.z);
            s6 += blo(v.w); s7 += bhi(v.w);
        }
        s0 += __shfl_xor(s0, 32); s1 += __shfl_xor(s1, 32);
        s2 += __shfl_xor(s2, 32); s3 += __shfl_xor(s3, 32);
        s4 += __shfl_xor(s4, 32); s5 += __shfl_xor(s5, 32);
        s6 += __shfl_xor(s6, 32); s7 += __shfl_xor(s7, 32);
        s0 += __shfl_xor(s0, 16); s1 += __shfl_xor(s1, 16);
        s2 += __shfl_xor(s2, 16); s3 += __shfl_xor(s3, 16);
        s4 += __shfl_xor(s4, 16); s5 += __shfl_xor(s5, 16);
        s6 += __shfl_xor(s6, 16); s7 += __shfl_xor(s7, 16);
        s0 += __shfl_xor(s0, 8);  s1 += __shfl_xor(s1, 8);
        s2 += __shfl_xor(s2, 8);  s3 += __shfl_xor(s3, 8);
        s4 += __shfl_xor(s4, 8);  s5 += __shfl_xor(s5, 8);
        s6 += __shfl_xor(s6, 8);  s7 += __shfl_xor(s7, 8);
        if (lane < 8) {
            uint4 rv = *reinterpret_cast<const uint4*>(r1 + (size_t)node * 64 + j * 8);
            float v0 = fmaxf(s0 + blo(rv.x), 0.f);
            float v1 = fmaxf(s1 + bhi(rv.x), 0.f);
            float v2 = fmaxf(s2 + blo(rv.y), 0.f);
            float v3 = fmaxf(s3 + bhi(rv.y), 0.f);
            float v4 = fmaxf(s4 + blo(rv.z), 0.f);
            float v5 = fmaxf(s5 + bhi(rv.z), 0.f);
            float v6 = fmaxf(s6 + blo(rv.w), 0.f);
            float v7 = fmaxf(s7 + bhi(rv.w), 0.f);
            uint4 o;
            o.x = pk2(v0, v1); o.y = pk2(v2, v3);
            o.z = pk2(v4, v5); o.w = pk2(v6, v7);
            // swizzled 16B slot: phys = j ^ (w&7)
            unsigned byte = (unsigned)w * 128u + (((unsigned)j * 16u) ^ (((unsigned)w & 7u) << 4));
            *reinterpret_cast<uint4*>((char*)hlds + byte) = o;
        }
    }
    __syncthreads();

    // ---- Phase 2: 2 waves project the block's 16-row tile ----
    if (w >= 2) return;
    int row0 = blockIdx.x * 16;
    if (row0 >= N_NODES) return;
    int c15 = lane & 15;
    int q   = lane >> 4;

    const float* W = w ? Wroot : Wrel;
    bf16x8 bf[2][2];   // [ct][kf], sigma-compensated W2
#pragma unroll
    for (int ct = 0; ct < 2; ++ct) {
        int c = ct * 16 + c15;
#pragma unroll
        for (int kf = 0; kf < 2; ++kf) {
            bf16x8 f;
#pragma unroll
            for (int jj = 0; jj < 8; ++jj) {
                int p = kf * 32 + q * 8 + jj;
                int tk = (p & 3) * 16 + (p >> 2);   // sigma(p)
                f[jj] = (short)f2b(W[tk * 32 + c]);
            }
            bf[ct][kf] = f;
        }
    }
    float bv[2];
#pragma unroll
    for (int ct = 0; ct < 2; ++ct) bv[ct] = w ? bias[ct * 16 + c15] : 0.0f;

    int r = c15;                       // local LDS row
    unsigned sw = ((unsigned)r & 7u) << 4;
    bf16x8 a0 = *reinterpret_cast<const bf16x8*>((char*)hlds + (unsigned)r * 128u + (((unsigned)q * 16u) ^ sw));
    bf16x8 a1 = *reinterpret_cast<const bf16x8*>((char*)hlds + (unsigned)r * 128u + ((((unsigned)q + 4u) * 16u) ^ sw));

    floatx4 z = {0.f, 0.f, 0.f, 0.f};
    floatx4 acc[2];
#pragma unroll
    for (int ct = 0; ct < 2; ++ct) {
        floatx4 a = __builtin_amdgcn_mfma_f32_16x16x32_bf16(a0, bf[ct][0], z, 0, 0, 0);
        acc[ct] = __builtin_amdgcn_mfma_f32_16x16x32_bf16(a1, bf[ct][1], a, 0, 0, 0);
    }

    unsigned short* dst = w ? r2 : u2;
    // sigma2-order write (position 2i <-> col i, 2i+1 <-> col 16+i)
#pragma unroll
    for (int reg = 0; reg < 4; ++reg) {
        int row = row0 + q * 4 + reg;
        unsigned vv = pk2(acc[0][reg] + bv[0], acc[1][reg] + bv[1]);
        *reinterpret_cast<unsigned*>(dst + (size_t)row * 32 + c15 * 2) = vv;
    }
}

// ---------------------------------------------------------------------------
// Aggregate layer 2 (sigma2-order bf16 in) -> TRUE row-major f32 out.
// Wave/node; 4 lanes x uint4 per row; 16 edge slots in flight.
// ---------------------------------------------------------------------------
__global__ __launch_bounds__(256) void k_agg32(
    const unsigned short* __restrict__ u2,
    const unsigned short* __restrict__ r2,
    const int* __restrict__ offsets, const int* __restrict__ esrc,
    float* __restrict__ out)
{
    int lane = threadIdx.x & 63;
    int node = (blockIdx.x * blockDim.x + threadIdx.x) >> 6;
    if (node >= N_NODES) return;
    int j    = lane & 3;        // 4 lanes/row, 16B each
    int slot = lane >> 2;       // 16 edge slots
    int beg = offsets[node], end = offsets[node + 1];
    float s0 = 0.f, s1 = 0.f, s2 = 0.f, s3 = 0.f;
    float s4 = 0.f, s5 = 0.f, s6 = 0.f, s7 = 0.f;
    for (int e = beg + slot; e < end; e += 16) {
        int sv = esrc[e];
        uint4 v = *reinterpret_cast<const uint4*>(u2 + (size_t)sv * 32 + j * 8);
        s0 += blo(v.x); s1 += bhi(v.x);
        s2 += blo(v.y); s3 += bhi(v.y);
        s4 += blo(v.z); s5 += bhi(v.z);
        s6 += blo(v.w); s7 += bhi(v.w);
    }
    s0 += __shfl_xor(s0, 32); s1 += __shfl_xor(s1, 32);
    s2 += __shfl_xor(s2, 32); s3 += __shfl_xor(s3, 32);
    s4 += __shfl_xor(s4, 32); s5 += __shfl_xor(s5, 32);
    s6 += __shfl_xor(s6, 32); s7 += __shfl_xor(s7, 32);
    s0 += __shfl_xor(s0, 16); s1 += __shfl_xor(s1, 16);
    s2 += __shfl_xor(s2, 16); s3 += __shfl_xor(s3, 16);
    s4 += __shfl_xor(s4, 16); s5 += __shfl_xor(s5, 16);
    s6 += __shfl_xor(s6, 16); s7 += __shfl_xor(s7, 16);
    s0 += __shfl_xor(s0, 8);  s1 += __shfl_xor(s1, 8);
    s2 += __shfl_xor(s2, 8);  s3 += __shfl_xor(s3, 8);
    s4 += __shfl_xor(s4, 8);  s5 += __shfl_xor(s5, 8);
    s6 += __shfl_xor(s6, 8);  s7 += __shfl_xor(s7, 8);
    s0 += __shfl_xor(s0, 4);  s1 += __shfl_xor(s1, 4);
    s2 += __shfl_xor(s2, 4);  s3 += __shfl_xor(s3, 4);
    s4 += __shfl_xor(s4, 4);  s5 += __shfl_xor(s5, 4);
    s6 += __shfl_xor(s6, 4);  s7 += __shfl_xor(s7, 4);
    if (lane < 4) {
        // sigma2: pair k=j*4+i holds (col k, col 16+k) in (lo,hi)
        uint4 rv = *reinterpret_cast<const uint4*>(r2 + (size_t)node * 32 + j * 8);
        float4 oA, oB;
        oA.x = s0 + blo(rv.x);  oB.x = s1 + bhi(rv.x);
        oA.y = s2 + blo(rv.y);  oB.y = s3 + bhi(rv.y);
        oA.z = s4 + blo(rv.z);  oB.z = s5 + bhi(rv.z);
        oA.w = s6 + blo(rv.w);  oB.w = s7 + bhi(rv.w);
        *reinterpret_cast<float4*>(out + (size_t)node * 32 + j * 4)      = oA;
        *reinterpret_cast<float4*>(out + (size_t)node * 32 + 16 + j * 4) = oB;
    }
}

extern "C" void kernel_launch(void* const* d_in, const int* in_sizes, int n_in,
                              void* d_out, int out_size, void* d_ws, size_t ws_size,
                              hipStream_t stream) {
    const float* x      = (const float*)d_in[0];
    const int*   ei     = (const int*)  d_in[1];
    const float* Wrel1  = (const float*)d_in[2];
    const float* Wroot1 = (const float*)d_in[3];
    const float* b1     = (const float*)d_in[4];
    const float* Wrel2  = (const float*)d_in[5];
    const float* Wroot2 = (const float*)d_in[6];
    const float* b2     = (const float*)d_in[7];
    float*       out    = (float*)d_out;

    const int* srcv = ei;
    const int* dstv = ei + N_EDGES;

    char* p = (char*)d_ws;
    auto alloc = [&](size_t bytes) {
        char* r = p;
        p += (bytes + 255) & ~(size_t)255;
        return r;
    };
    int*      offsets = (int*)     alloc(sizeof(int) * (N_NODES + 1));
    int*      bcnt    = (int*)     alloc(sizeof(int) * NBK);
    unsigned* epair   = (unsigned*)alloc(sizeof(unsigned) * (size_t)NBK * BCAP);
    int*      esrc    = (int*)     alloc(sizeof(int) * N_EDGES);
    unsigned short* u1 = (unsigned short*)alloc(sizeof(short) * (size_t)N_NODES * 64);
    unsigned short* r1 = (unsigned short*)alloc(sizeof(short) * (size_t)N_NODES * 64);
    unsigned short* u2 = (unsigned short*)alloc(sizeof(short) * (size_t)N_NODES * 32);
    unsigned short* r2 = (unsigned short*)alloc(sizeof(short) * (size_t)N_NODES * 32);

    const int nodeBlocks = (N_NODES * 64 + 255) / 256;   // wave per node (agg32)
    const int aggfBlocks = (N_NODES + 15) / 16;          // 16 nodes per block

    // CSR build + layer-1 projection (independent -> one fused dispatch)
    hipMemsetAsync(bcnt, 0, sizeof(int) * NBK, stream);
    k_binpre1<<<BIN_BLOCKS + PRE1_BLOCKS, 256, 0, stream>>>(
        srcv, dstv, bcnt, epair, x, Wrel1, Wroot1, b1, u1, r1);
    k_build<<<NBK, 512, 0, stream>>>(epair, bcnt, offsets, esrc);

    // Fused aggregate-1 + layer-2 projection (wave-per-node + MFMA from LDS)
    k_aggf<<<aggfBlocks, 1024, 0, stream>>>(u1, r1, offsets, esrc,
                                            Wrel2, Wroot2, b2, u2, r2);

    // Aggregate layer 2
    k_agg32<<<nodeBlocks, 256, 0, stream>>>(u2, r2, offsets, esrc, out);
}

// Round 13
// 86.441 us; speedup vs baseline: 1.0410x; 1.0410x over previous
//
#include <hip/hip_runtime.h>

static constexpr int N_NODES = 50000;
static constexpr int N_EDGES = 800000;

static constexpr int NBK      = 196;     // buckets of 256 dst-nodes (dst>>8)
static constexpr int BCAP     = 5120;    // slots/bucket (mean 4096, +16 sigma)
static constexpr int MAXE     = BCAP / 512;   // 10 elems/thread in k_build
static constexpr int BIN_TILE = 4096;    // edges per bin block
static constexpr int BIN_BLOCKS = (N_EDGES + BIN_TILE - 1) / BIN_TILE;  // 196
static constexpr int PRE1_TILES  = (N_NODES + 15) / 16;                 // 3125
static constexpr int PRE1_BLOCKS = (PRE1_TILES + 3) / 4;                // 782

typedef __attribute__((ext_vector_type(8))) short   bf16x8;
typedef __attribute__((ext_vector_type(4))) float   floatx4;

// f32 -> bf16 (RNE) as raw u16
__device__ __forceinline__ unsigned short f2b(float f) {
    union { float f; unsigned u; } v; v.f = f;
    unsigned r = v.u + 0x7FFFu + ((v.u >> 16) & 1u);
    return (unsigned short)(r >> 16);
}
__device__ __forceinline__ float blo(unsigned v) {
    union { unsigned u; float f; } c; c.u = v << 16; return c.f;
}
__device__ __forceinline__ float bhi(unsigned v) {
    union { unsigned u; float f; } c; c.u = v & 0xffff0000u; return c.f;
}
__device__ __forceinline__ unsigned pk2(float a, float b) {
    return (unsigned)f2b(a) | ((unsigned)f2b(b) << 16);
}

// ---------------------------------------------------------------------------
// Fused dispatch 1: blocks [0, BIN_BLOCKS) bin edges into 196 dst-buckets;
// blocks [BIN_BLOCKS, +PRE1_BLOCKS) run the MFMA layer-1 projection.
// ---------------------------------------------------------------------------
__device__ __forceinline__ void bin_body(
    int bb, const int* __restrict__ srcv, const int* __restrict__ dstv,
    int* __restrict__ bcnt, unsigned* __restrict__ epair)
{
    __shared__ unsigned stage[BIN_TILE];   // 16 KB, packed (src<<16|dst)
    __shared__ int cnt[256];
    __shared__ int scn[256];
    __shared__ int wtot[4], wbase[4];
    __shared__ int pref[NBK];
    __shared__ int gbase[NBK];

    int tid   = threadIdx.x;
    int lane  = tid & 63;
    int wv    = tid >> 6;
    int base  = bb * BIN_TILE;
    int tileN = min(BIN_TILE, N_EDGES - base);

    cnt[tid] = 0;
    __syncthreads();

    unsigned pk[16]; int sl[16];
#pragma unroll
    for (int j = 0; j < 16; ++j) {
        int i = tid + j * 256;
        pk[j] = 0xFFFFFFFFu; sl[j] = 0;
        if (i < tileN) {
            unsigned s = (unsigned)srcv[base + i];
            unsigned d = (unsigned)dstv[base + i];
            pk[j] = (s << 16) | d;
            sl[j] = atomicAdd(&cnt[d >> 8], 1);   // LDS only
        }
    }
    __syncthreads();

    // exclusive scan of cnt[0..255]: per-wave shfl scan + cross-wave fixup
    {
        int v = cnt[tid];
        int orig = v;
        for (int off = 1; off < 64; off <<= 1) {
            int t2 = __shfl_up(v, off);
            if (lane >= off) v += t2;
        }
        scn[tid] = v - orig;              // wave-local exclusive
        if (lane == 63) wtot[wv] = v;     // wave total
    }
    __syncthreads();
    if (tid == 0) {
        int r = 0;
#pragma unroll
        for (int k = 0; k < 4; ++k) { int t2 = wtot[k]; wbase[k] = r; r += t2; }
    }
    __syncthreads();
    if (tid < NBK) {
        pref[tid]  = scn[tid] + wbase[wv];
        gbase[tid] = tid * BCAP + atomicAdd(&bcnt[tid], cnt[tid]);
    }
    __syncthreads();

#pragma unroll
    for (int j = 0; j < 16; ++j) {
        if (pk[j] != 0xFFFFFFFFu) {
            int b = (int)((pk[j] & 0xFFFFu) >> 8);
            stage[pref[b] + sl[j]] = pk[j];
        }
    }
    __syncthreads();

    for (int i = tid; i < tileN; i += 256) {
        unsigned pd = stage[i];
        int b = (int)((pd & 0xFFFFu) >> 8);
        epair[(size_t)gbase[b] + (i - pref[b])] = ((pd >> 16) << 8) | (pd & 255u);
    }
}

__device__ __forceinline__ void pre1_body(
    int bb, const float* __restrict__ x,
    const float* __restrict__ Wrel, const float* __restrict__ Wroot,
    const float* __restrict__ bias,
    unsigned short* __restrict__ u1, unsigned short* __restrict__ r1)
{
    int lane = threadIdx.x & 63;
    int c15  = lane & 15;
    int q    = lane >> 4;

    bf16x8 bf[2][4][2];
#pragma unroll
    for (int mat = 0; mat < 2; ++mat) {
        const float* W = mat ? Wroot : Wrel;
#pragma unroll
        for (int ct = 0; ct < 4; ++ct) {
            int c = ct * 16 + c15;
#pragma unroll
            for (int kf = 0; kf < 2; ++kf) {
                int kb = kf * 32 + q * 8;
                bf16x8 f;
#pragma unroll
                for (int j = 0; j < 8; ++j)
                    f[j] = (short)f2b(W[(kb + j) * 64 + c]);
                bf[mat][ct][kf] = f;
            }
        }
    }
    float bv[4];
#pragma unroll
    for (int ct = 0; ct < 4; ++ct) bv[ct] = bias[ct * 16 + c15];

    int tile = bb * 4 + (threadIdx.x >> 6);
    if (tile * 16 >= N_NODES) return;
    int row0 = tile * 16;

    const float* xr = x + (size_t)(row0 + c15) * 64;
    bf16x8 a0, a1;
#pragma unroll
    for (int j = 0; j < 8; ++j) {
        a0[j] = (short)f2b(xr[q * 8 + j]);
        a1[j] = (short)f2b(xr[32 + q * 8 + j]);
    }

    floatx4 z = {0.f, 0.f, 0.f, 0.f};
    floatx4 acc[2][4];
#pragma unroll
    for (int mat = 0; mat < 2; ++mat)
#pragma unroll
        for (int ct = 0; ct < 4; ++ct) {
            floatx4 a = __builtin_amdgcn_mfma_f32_16x16x32_bf16(a0, bf[mat][ct][0], z, 0, 0, 0);
            acc[mat][ct] = __builtin_amdgcn_mfma_f32_16x16x32_bf16(a1, bf[mat][ct][1], a, 0, 0, 0);
        }

    // sigma-order write: position p=(lane&15)*4+ct <-> true col ct*16+(lane&15)
#pragma unroll
    for (int reg = 0; reg < 4; ++reg) {
        int row = row0 + q * 4 + reg;
        uint2 uu, rr;
        uu.x = pk2(acc[0][0][reg],          acc[0][1][reg]);
        uu.y = pk2(acc[0][2][reg],          acc[0][3][reg]);
        rr.x = pk2(acc[1][0][reg] + bv[0],  acc[1][1][reg] + bv[1]);
        rr.y = pk2(acc[1][2][reg] + bv[2],  acc[1][3][reg] + bv[3]);
        *reinterpret_cast<uint2*>(u1 + (size_t)row * 64 + c15 * 4) = uu;
        *reinterpret_cast<uint2*>(r1 + (size_t)row * 64 + c15 * 4) = rr;
    }
}

__global__ __launch_bounds__(256) void k_binpre1(
    const int* __restrict__ srcv, const int* __restrict__ dstv,
    int* __restrict__ bcnt, unsigned* __restrict__ epair,
    const float* __restrict__ x,
    const float* __restrict__ Wrel, const float* __restrict__ Wroot,
    const float* __restrict__ bias,
    unsigned short* __restrict__ u1, unsigned short* __restrict__ r1)
{
    if ((int)blockIdx.x < BIN_BLOCKS)
        bin_body(blockIdx.x, srcv, dstv, bcnt, epair);
    else
        pre1_body(blockIdx.x - BIN_BLOCKS, x, Wrel, Wroot, bias, u1, r1);
}

// ---------------------------------------------------------------------------
// Dispatch 2: one block per 256-node bucket; single pass over packed pairs in
// statically-indexed registers; LDS histogram + wave-shfl scan; atomic-free
// scatter.
// ---------------------------------------------------------------------------
__global__ __launch_bounds__(512) void k_build(
    const unsigned* __restrict__ epair, const int* __restrict__ bcnt,
    int* __restrict__ offsets, int* __restrict__ esrc)
{
    __shared__ int cnt[256];
    __shared__ int scn[256];
    __shared__ int start[256];
    __shared__ int wtot[4], wbase[4];
    __shared__ int s_base;

    int b = blockIdx.x;
    int t = threadIdx.x;
    int lane = t & 63;
    int node0 = b << 8;
    int ncnt  = min(256, N_NODES - node0);
    int beg   = b * BCAP;
    int m     = bcnt[b];

    if (t < 256) cnt[t] = 0;
    __syncthreads();

    unsigned ev[MAXE]; int sl[MAXE];
#pragma unroll
    for (int j = 0; j < MAXE; ++j) {
        int i = t + j * 512;
        ev[j] = 0; sl[j] = -1;
        if (i < m) {
            ev[j] = epair[beg + i];
            sl[j] = atomicAdd(&cnt[ev[j] & 255u], 1);
        }
    }

    // bucket global base = total size of earlier buckets (first wave)
    if (t < 64) {
        int pre = 0;
#pragma unroll
        for (int k = 0; k < 4; ++k) {
            int i = t + (k << 6);
            if (i < b) pre += bcnt[i];
        }
        for (int off = 1; off < 64; off <<= 1) pre += __shfl_xor(pre, off);
        if (t == 0) s_base = pre;
    }
    __syncthreads();

    // exclusive scan of cnt[0..255]: wave shfl scan + cross-wave fixup
    if (t < 256) {
        int v = cnt[t];
        int orig = v;
        for (int off = 1; off < 64; off <<= 1) {
            int t2 = __shfl_up(v, off);
            if (lane >= off) v += t2;
        }
        scn[t] = v - orig;
        if (lane == 63) wtot[t >> 6] = v;
    }
    __syncthreads();
    if (t == 0) {
        int r = 0;
#pragma unroll
        for (int k = 0; k < 4; ++k) { int q = wtot[k]; wbase[k] = r; r += q; }
    }
    __syncthreads();
    if (t < 256) {
        int st = s_base + scn[t] + wbase[t >> 6];
        start[t] = st;
        if (t < ncnt) offsets[node0 + t] = st;
    }
    if (b == 0 && t == 0) offsets[N_NODES] = N_EDGES;
    __syncthreads();

#pragma unroll
    for (int j = 0; j < MAXE; ++j) {
        if (sl[j] >= 0)
            esrc[start[ev[j] & 255u] + sl[j]] = (int)(ev[j] >> 8);
    }
}

// ---------------------------------------------------------------------------
// FUSED aggregate-1 + layer-2 projection, WAVE-PER-NODE:
// block = 16 waves = 16 nodes, each wave gathers ONE node in parallel
// (full node TLP preserved), h rows -> XOR-swizzled LDS; after the barrier
// wave0 projects u2 = h@Wrel2, wave1 projects r2 = h@Wroot2+b2 (MFMA).
// ---------------------------------------------------------------------------
__global__ __launch_bounds__(1024) void k_aggf(
    const unsigned short* __restrict__ u1,
    const unsigned short* __restrict__ r1,
    const int* __restrict__ offsets, const int* __restrict__ esrc,
    const float* __restrict__ Wrel,    // [64][32] f32
    const float* __restrict__ Wroot,   // [64][32] f32
    const float* __restrict__ bias,    // [32] f32
    unsigned short* __restrict__ u2,
    unsigned short* __restrict__ r2)
{
    __shared__ unsigned short hlds[16 * 64];   // 2 KB, swizzled rows

    int w    = threadIdx.x >> 6;   // 0..15 = local node
    int lane = threadIdx.x & 63;
    int j    = lane & 7;           // 8 lanes/row, 16B each
    int slot = lane >> 3;          // 8 edge slots

    int node = blockIdx.x * 16 + w;   // N_NODES = 3125*16 exactly
    if (node < N_NODES) {
        int beg = offsets[node], end = offsets[node + 1];
        float s0 = 0.f, s1 = 0.f, s2 = 0.f, s3 = 0.f;
        float s4 = 0.f, s5 = 0.f, s6 = 0.f, s7 = 0.f;
        for (int e = beg + slot; e < end; e += 8) {
            int sv = esrc[e];
            uint4 v = *reinterpret_cast<const uint4*>(u1 + (size_t)sv * 64 + j * 8);
            s0 += blo(v.x); s1 += bhi(v.x);
            s2 += blo(v.y); s3 += bhi(v.y);
            s4 += blo(v.z); s5 += bhi(v.z);
            s6 += blo(v.w); s7 += bhi(v.w);
        }
        s0 += __shfl_xor(s0, 32); s1 += __shfl_xor(s1, 32);
        s2 += __shfl_xor(s2, 32); s3 += __shfl_xor(s3, 32);
        s4 += __shfl_xor(s4, 32); s5 += __shfl_xor(s5, 32);
        s6 += __shfl_xor(s6, 32); s7 += __shfl_xor(s7, 32);
        s0 += __shfl_xor(s0, 16); s1 += __shfl_xor(s1, 16);
        s2 += __shfl_xor(s2, 16); s3 += __shfl_xor(s3, 16);
        s4 += __shfl_xor(s4, 16); s5 += __shfl_xor(s5, 16);
        s6 += __shfl_xor(s6, 16); s7 += __shfl_xor(s7, 16);
        s0 += __shfl_xor(s0, 8);  s1 += __shfl_xor(s1, 8);
        s2 += __shfl_xor(s2, 8);  s3 += __shfl_xor(s3, 8);
        s4 += __shfl_xor(s4, 8);  s5 += __shfl_xor(s5, 8);
        s6 += __shfl_xor(s6, 8);  s7 += __shfl_xor(s7, 8);
        if (lane < 8) {
            uint4 rv = *reinterpret_cast<const uint4*>(r1 + (size_t)node * 64 + j * 8);
            float v0 = fmaxf(s0 + blo(rv.x), 0.f);
            float v1 = fmaxf(s1 + bhi(rv.x), 0.f);
            float v2 = fmaxf(s2 + blo(rv.y), 0.f);
            float v3 = fmaxf(s3 + bhi(rv.y), 0.f);
            float v4 = fmaxf(s4 + blo(rv.z), 0.f);
            float v5 = fmaxf(s5 + bhi(rv.z), 0.f);
            float v6 = fmaxf(s6 + blo(rv.w), 0.f);
            float v7 = fmaxf(s7 + bhi(rv.w), 0.f);
            uint4 o;
            o.x = pk2(v0, v1); o.y = pk2(v2, v3);
            o.z = pk2(v4, v5); o.w = pk2(v6, v7);
            // swizzled 16B slot: phys = j ^ (w&7)
            unsigned byte = (unsigned)w * 128u + (((unsigned)j * 16u) ^ (((unsigned)w & 7u) << 4));
            *reinterpret_cast<uint4*>((char*)hlds + byte) = o;
        }
    }
    __syncthreads();

    // ---- Phase 2: 2 waves project the block's 16-row tile ----
    if (w >= 2) return;
    int row0 = blockIdx.x * 16;
    if (row0 >= N_NODES) return;
    int c15 = lane & 15;
    int q   = lane >> 4;

    const float* W = w ? Wroot : Wrel;
    bf16x8 bf[2][2];   // [ct][kf], sigma-compensated W2
#pragma unroll
    for (int ct = 0; ct < 2; ++ct) {
        int c = ct * 16 + c15;
#pragma unroll
        for (int kf = 0; kf < 2; ++kf) {
            bf16x8 f;
#pragma unroll
            for (int jj = 0; jj < 8; ++jj) {
                int p = kf * 32 + q * 8 + jj;
                int tk = (p & 3) * 16 + (p >> 2);   // sigma(p)
                f[jj] = (short)f2b(W[tk * 32 + c]);
            }
            bf[ct][kf] = f;
        }
    }
    float bv[2];
#pragma unroll
    for (int ct = 0; ct < 2; ++ct) bv[ct] = w ? bias[ct * 16 + c15] : 0.0f;

    int r = c15;                       // local LDS row
    unsigned sw = ((unsigned)r & 7u) << 4;
    bf16x8 a0 = *reinterpret_cast<const bf16x8*>((char*)hlds + (unsigned)r * 128u + (((unsigned)q * 16u) ^ sw));
    bf16x8 a1 = *reinterpret_cast<const bf16x8*>((char*)hlds + (unsigned)r * 128u + ((((unsigned)q + 4u) * 16u) ^ sw));

    floatx4 z = {0.f, 0.f, 0.f, 0.f};
    floatx4 acc[2];
#pragma unroll
    for (int ct = 0; ct < 2; ++ct) {
        floatx4 a = __builtin_amdgcn_mfma_f32_16x16x32_bf16(a0, bf[ct][0], z, 0, 0, 0);
        acc[ct] = __builtin_amdgcn_mfma_f32_16x16x32_bf16(a1, bf[ct][1], a, 0, 0, 0);
    }

    unsigned short* dst = w ? r2 : u2;
    // sigma2-order write (position 2i <-> col i, 2i+1 <-> col 16+i)
#pragma unroll
    for (int reg = 0; reg < 4; ++reg) {
        int row = row0 + q * 4 + reg;
        unsigned vv = pk2(acc[0][reg] + bv[0], acc[1][reg] + bv[1]);
        *reinterpret_cast<unsigned*>(dst + (size_t)row * 32 + c15 * 2) = vv;
    }
}

// ---------------------------------------------------------------------------
// Aggregate layer 2 (sigma2-order bf16 in) -> TRUE row-major f32 out.
// Wave/node; 4 lanes x uint4 per row; 16 edge slots in flight.
// ---------------------------------------------------------------------------
__global__ __launch_bounds__(256) void k_agg32(
    const unsigned short* __restrict__ u2,
    const unsigned short* __restrict__ r2,
    const int* __restrict__ offsets, const int* __restrict__ esrc,
    float* __restrict__ out)
{
    int lane = threadIdx.x & 63;
    int node = (blockIdx.x * blockDim.x + threadIdx.x) >> 6;
    if (node >= N_NODES) return;
    int j    = lane & 3;        // 4 lanes/row, 16B each
    int slot = lane >> 2;       // 16 edge slots
    int beg = offsets[node], end = offsets[node + 1];
    float s0 = 0.f, s1 = 0.f, s2 = 0.f, s3 = 0.f;
    float s4 = 0.f, s5 = 0.f, s6 = 0.f, s7 = 0.f;
    for (int e = beg + slot; e < end; e += 16) {
        int sv = esrc[e];
        uint4 v = *reinterpret_cast<const uint4*>(u2 + (size_t)sv * 32 + j * 8);
        s0 += blo(v.x); s1 += bhi(v.x);
        s2 += blo(v.y); s3 += bhi(v.y);
        s4 += blo(v.z); s5 += bhi(v.z);
        s6 += blo(v.w); s7 += bhi(v.w);
    }
    s0 += __shfl_xor(s0, 32); s1 += __shfl_xor(s1, 32);
    s2 += __shfl_xor(s2, 32); s3 += __shfl_xor(s3, 32);
    s4 += __shfl_xor(s4, 32); s5 += __shfl_xor(s5, 32);
    s6 += __shfl_xor(s6, 32); s7 += __shfl_xor(s7, 32);
    s0 += __shfl_xor(s0, 16); s1 += __shfl_xor(s1, 16);
    s2 += __shfl_xor(s2, 16); s3 += __shfl_xor(s3, 16);
    s4 += __shfl_xor(s4, 16); s5 += __shfl_xor(s5, 16);
    s6 += __shfl_xor(s6, 16); s7 += __shfl_xor(s7, 16);
    s0 += __shfl_xor(s0, 8);  s1 += __shfl_xor(s1, 8);
    s2 += __shfl_xor(s2, 8);  s3 += __shfl_xor(s3, 8);
    s4 += __shfl_xor(s4, 8);  s5 += __shfl_xor(s5, 8);
    s6 += __shfl_xor(s6, 8);  s7 += __shfl_xor(s7, 8);
    s0 += __shfl_xor(s0, 4);  s1 += __shfl_xor(s1, 4);
    s2 += __shfl_xor(s2, 4);  s3 += __shfl_xor(s3, 4);
    s4 += __shfl_xor(s4, 4);  s5 += __shfl_xor(s5, 4);
    s6 += __shfl_xor(s6, 4);  s7 += __shfl_xor(s7, 4);
    if (lane < 4) {
        // sigma2: pair k=j*4+i holds (col k, col 16+k) in (lo,hi)
        uint4 rv = *reinterpret_cast<const uint4*>(r2 + (size_t)node * 32 + j * 8);
        float4 oA, oB;
        oA.x = s0 + blo(rv.x);  oB.x = s1 + bhi(rv.x);
        oA.y = s2 + blo(rv.y);  oB.y = s3 + bhi(rv.y);
        oA.z = s4 + blo(rv.z);  oB.z = s5 + bhi(rv.z);
        oA.w = s6 + blo(rv.w);  oB.w = s7 + bhi(rv.w);
        *reinterpret_cast<float4*>(out + (size_t)node * 32 + j * 4)      = oA;
        *reinterpret_cast<float4*>(out + (size_t)node * 32 + 16 + j * 4) = oB;
    }
}

extern "C" void kernel_launch(void* const* d_in, const int* in_sizes, int n_in,
                              void* d_out, int out_size, void* d_ws, size_t ws_size,
                              hipStream_t stream) {
    const float* x      = (const float*)d_in[0];
    const int*   ei     = (const int*)  d_in[1];
    const float* Wrel1  = (const float*)d_in[2];
    const float* Wroot1 = (const float*)d_in[3];
    const float* b1     = (const float*)d_in[4];
    const float* Wrel2  = (const float*)d_in[5];
    const float* Wroot2 = (const float*)d_in[6];
    const float* b2     = (const float*)d_in[7];
    float*       out    = (float*)d_out;

    const int* srcv = ei;
    const int* dstv = ei + N_EDGES;

    char* p = (char*)d_ws;
    auto alloc = [&](size_t bytes) {
        char* r = p;
        p += (bytes + 255) & ~(size_t)255;
        return r;
    };
    int*      offsets = (int*)     alloc(sizeof(int) * (N_NODES + 1));
    int*      bcnt    = (int*)     alloc(sizeof(int) * NBK);
    unsigned* epair   = (unsigned*)alloc(sizeof(unsigned) * (size_t)NBK * BCAP);
    int*      esrc    = (int*)     alloc(sizeof(int) * N_EDGES);
    unsigned short* u1 = (unsigned short*)alloc(sizeof(short) * (size_t)N_NODES * 64);
    unsigned short* r1 = (unsigned short*)alloc(sizeof(short) * (size_t)N_NODES * 64);
    unsigned short* u2 = (unsigned short*)alloc(sizeof(short) * (size_t)N_NODES * 32);
    unsigned short* r2 = (unsigned short*)alloc(sizeof(short) * (size_t)N_NODES * 32);

    const int nodeBlocks = (N_NODES * 64 + 255) / 256;   // wave per node (agg32)
    const int aggfBlocks = (N_NODES + 15) / 16;          // 16 nodes per block

    // CSR build + layer-1 projection (independent -> one fused dispatch)
    hipMemsetAsync(bcnt, 0, sizeof(int) * NBK, stream);
    k_binpre1<<<BIN_BLOCKS + PRE1_BLOCKS, 256, 0, stream>>>(
        srcv, dstv, bcnt, epair, x, Wrel1, Wroot1, b1, u1, r1);
    k_build<<<NBK, 512, 0, stream>>>(epair, bcnt, offsets, esrc);

    // Fused aggregate-1 + layer-2 projection (wave-per-node + MFMA from LDS)
    k_aggf<<<aggfBlocks, 1024, 0, stream>>>(u1, r1, offsets, esrc,
                                            Wrel2, Wroot2, b2, u2, r2);

    // Aggregate layer 2
    k_agg32<<<nodeBlocks, 256, 0, stream>>>(u2, r2, offsets, esrc, out);
}